// Round 15
// baseline (197.459 us; speedup 1.0000x reference)
//
#include <hip/hip_runtime.h>

typedef __bf16 bf16x8 __attribute__((ext_vector_type(8)));
typedef float f32x4 __attribute__((ext_vector_type(4)));
typedef float f32x16 __attribute__((ext_vector_type(16)));
typedef unsigned int uint2v __attribute__((ext_vector_type(2)));

#define LOG2E 1.44269504088896340736f

#if __has_builtin(__builtin_amdgcn_exp2f)
#define EXP2(x) __builtin_amdgcn_exp2f(x)
#else
#define EXP2(x) exp2f(x)
#endif

static __device__ __forceinline__ unsigned short f2bf(float f) {
    unsigned int u = __builtin_bit_cast(unsigned int, f);
    u += 0x7fffu + ((u >> 16) & 1u);   // RNE
    return (unsigned short)(u >> 16);
}

static __device__ __forceinline__ void plswap(unsigned int& a, unsigned int& b) {
#if __has_builtin(__builtin_amdgcn_permlane32_swap)
    uint2v r = __builtin_amdgcn_permlane32_swap(a, b, false, false);
    a = r.x; b = r.y;
#else
    asm("v_permlane32_swap_b32 %0, %1" : "+v"(a), "+v"(b));
#endif
}

static __device__ __forceinline__ float xhalf_add(float x) {
    unsigned int a = __builtin_bit_cast(unsigned int, x), b = a;
    plswap(a, b);
    return __builtin_bit_cast(float, a) + __builtin_bit_cast(float, b);
}

// ---------------- fused fp32 -> bf16 convert (x | w_qkv | w_out in one launch) ----------------
__global__ void cvt3_kernel(const float* __restrict__ x, const float* __restrict__ wq,
                            const float* __restrict__ wo,
                            unsigned short* __restrict__ xb, unsigned short* __restrict__ wqb,
                            unsigned short* __restrict__ wob) {
    // flat float4 index space: x 2097152 | w_qkv 786432 | w_out 262144 = 3145728
    int i = blockIdx.x * blockDim.x + threadIdx.x;
    int stride = gridDim.x * blockDim.x;
    for (; i < 3145728; i += stride) {
        const float* src;
        unsigned short* dst;
        int j;
        if (i < 2097152)      { j = i;           src = x;  dst = xb;  }
        else if (i < 2883584) { j = i - 2097152; src = wq; dst = wqb; }
        else                  { j = i - 2883584; src = wo; dst = wob; }
        float4 v = reinterpret_cast<const float4*>(src)[j];
        ushort4 o;
        o.x = f2bf(v.x); o.y = f2bf(v.y); o.z = f2bf(v.z); o.w = f2bf(v.w);
        reinterpret_cast<ushort4*>(dst)[j] = o;
    }
}

// ---------------- bf16 GEMM, C = A * B^T (+bias) — r9-proven 2-phase structure ----------------
template <int MODE>
__global__ __launch_bounds__(256, 2) void gemm_bt(const unsigned short* __restrict__ A,
                                                  const unsigned short* __restrict__ B,
                                                  const float* __restrict__ bias,
                                                  void* __restrict__ Cout,
                                                  int M, int N, int K) {
    __shared__ unsigned short SH[2][2][128 * 64];   // [buf][A/B][128x64] = 64 KB
    const int tid = threadIdx.x;
    const int w = tid >> 6, lane = tid & 63;
    const int wr = w >> 1, wc = w & 1;
    const int bm0 = blockIdx.y << 7, bn0 = blockIdx.x << 7;
    const int l15 = lane & 15, l4 = lane >> 4;

    const int srow = w * 8 + (lane >> 3);
    const int gch = (lane & 7) ^ (lane >> 3);

    f32x4 acc[4][4] = {};

    auto stage = [&](int buf, int kt) {
        const int k0 = kt << 6;
        #pragma unroll
        for (int i = 0; i < 4; ++i) {
            int row = i * 32 + srow;
            const unsigned short* ga = A + (size_t)(bm0 + row) * K + k0 + gch * 8;
            __builtin_amdgcn_global_load_lds(
                (const __attribute__((address_space(1))) void*)ga,
                (__attribute__((address_space(3))) void*)&SH[buf][0][i * 2048 + w * 512],
                16, 0, 0);
            const unsigned short* gb = B + (size_t)(bn0 + row) * K + k0 + gch * 8;
            __builtin_amdgcn_global_load_lds(
                (const __attribute__((address_space(1))) void*)gb,
                (__attribute__((address_space(3))) void*)&SH[buf][1][i * 2048 + w * 512],
                16, 0, 0);
        }
    };

    const int nk = K >> 6;
    stage(0, 0);
    __syncthreads();
    int buf = 0;
    for (int kt = 0; kt < nk; ++kt) {
        if (kt + 1 < nk) stage(buf ^ 1, kt + 1);
        const unsigned short* as = &SH[buf][0][0];
        const unsigned short* bs = &SH[buf][1][0];
        #pragma unroll
        for (int s = 0; s < 2; ++s) {
            bf16x8 af[4], bfr[4];
            #pragma unroll
            for (int t = 0; t < 4; ++t) {
                int rowa = wr * 64 + t * 16 + l15;
                int cha = (s * 4 + l4) ^ (rowa & 7);
                af[t] = *(const bf16x8*)&as[rowa * 64 + cha * 8];
                int rowb = wc * 64 + t * 16 + l15;
                int chb = (s * 4 + l4) ^ (rowb & 7);
                bfr[t] = *(const bf16x8*)&bs[rowb * 64 + chb * 8];
            }
            #pragma unroll
            for (int i = 0; i < 4; ++i)
                #pragma unroll
                for (int j = 0; j < 4; ++j)
                    acc[i][j] = __builtin_amdgcn_mfma_f32_16x16x32_bf16(af[i], bfr[j], acc[i][j], 0, 0, 0);
        }
        __syncthreads();
        buf ^= 1;
    }

    if (MODE == 0) {
        unsigned short* O = (unsigned short*)Cout;
        if (bn0 >= 2048) {
            // V region: LDS-bounce transpose -> coalesced uint4 stores
            unsigned short* T = &SH[0][0][0];
            __syncthreads();
            #pragma unroll
            for (int j = 0; j < 4; ++j) {
                int cl = wc * 64 + j * 16 + l15;
                float bv = bias[bn0 + cl];
                #pragma unroll
                for (int i = 0; i < 4; ++i) {
                    int nl = wr * 64 + i * 16 + l4 * 4;
                    ushort4 pk;
                    pk.x = f2bf(acc[i][j][0] + bv);
                    pk.y = f2bf(acc[i][j][1] + bv);
                    pk.z = f2bf(acc[i][j][2] + bv);
                    pk.w = f2bf(acc[i][j][3] + bv);
                    *(ushort4*)&T[cl * 136 + nl] = pk;
                }
            }
            __syncthreads();
            const int b = bm0 >> 11, n0 = bm0 & 2047;
            const int h0 = (bn0 >> 6) & 15;
            #pragma unroll
            for (int it = 0; it < 8; ++it) {
                int dl = it * 16 + (tid >> 4);
                int ch = tid & 15;
                uint4 val = *(const uint4*)&T[dl * 136 + ch * 8];
                size_t idx = (size_t)16777216 +
                             ((size_t)((b * 16 + (h0 + (dl >> 6))) * 64 + (dl & 63))) * 2048 +
                             n0 + ch * 8;
                *(uint4*)&O[idx] = val;
            }
        } else {
            #pragma unroll
            for (int j = 0; j < 4; ++j) {
                int col = bn0 + wc * 64 + j * 16 + l15;
                float bv = bias[col];
                int which = col >> 10;
                int h = (col >> 6) & 15;
                int d = col & 63;
                #pragma unroll
                for (int i = 0; i < 4; ++i) {
                    #pragma unroll
                    for (int r = 0; r < 4; ++r) {
                        int row = bm0 + wr * 64 + i * 16 + l4 * 4 + r;
                        int b = row >> 11, n = row & 2047;
                        float v = acc[i][j][r] + bv;
                        size_t idx;
                        if (which == 0) { v *= 0.125f * LOG2E; idx = ((size_t)((b * 16 + h) * 2048 + n)) * 64 + d; }
                        else { idx = (size_t)8388608 + ((size_t)((b * 16 + h) * 2048 + n)) * 64 + d; }
                        O[idx] = f2bf(v);
                    }
                }
            }
        }
    } else {
        float* C = (float*)Cout;
        #pragma unroll
        for (int j = 0; j < 4; ++j) {
            int col = bn0 + wc * 64 + j * 16 + l15;
            float bv = bias[col];
            #pragma unroll
            for (int i = 0; i < 4; ++i) {
                #pragma unroll
                for (int r = 0; r < 4; ++r) {
                    int row = bm0 + wr * 64 + i * 16 + l4 * 4 + r;
                    C[(size_t)row * N + col] = acc[i][j][r] + bv;
                }
            }
        }
    }
}

// ---------------- flash attention v10: tile-pipelined (QK one tile ahead) ----------------
// r14 diagnosis: v7 (2 w/SIMD) == v9 (4 w/SIMD) == 80.5us; VALU 48% + MFMA 38% ~= wall
// => pipes NEVER overlap (barrier lockstep: all waves in same phase). Fix: break the
// intra-iteration QK->softmax->PV chain. 3-buffer LDS rotation; iter t computes
// QK(t+1) BEFORE softmax(t) so the MFMA pipe crunches next tile's QK under this
// tile's softmax VALU. Same frag layouts/swizzle/staging as v9; one barrier/iter;
// no cross-wave combine. Race audit: bufs t,t+1,t+2 mod 3 distinct; overwrite of
// buf[(t+2)%3] (tile t-1) ordered behind iter t-1 reads by iter t barrier; stage(t+1)
// landing guaranteed by iter t barrier's vmcnt drain.
__global__ __launch_bounds__(512, 2) void attn_kernel(const unsigned short* __restrict__ qkv,
                                                      unsigned short* __restrict__ out) {
    __shared__ unsigned short Klds[3][4096];   // [64 k-rows][64 d] per buf
    __shared__ unsigned short Vlds[3][4096];   // [64 d-rows][64 n] per buf

    const int tid = threadIdx.x;
    const int w = tid >> 6, lane = tid & 63;   // w in [0,8)
    const int ql = lane & 31;
    const int hi = lane >> 5;
    const int id = blockIdx.x;       // 0..511
    const int bh = id & 63;          // all 8 q-tiles of a head land on one XCD
    const int qt = id >> 6;          // 0..7
    const size_t SEC = 8388608;

    const unsigned short* Q  = qkv + (size_t)bh * (2048 * 64);
    const unsigned short* Kp = qkv + SEC + (size_t)bh * (2048 * 64);
    const unsigned short* Vt = qkv + 2 * SEC + (size_t)bh * (64 * 2048);

    const int q0 = qt * 256 + w * 32;

    bf16x8 qb[4];
    #pragma unroll
    for (int c = 0; c < 4; ++c)
        qb[c] = *(const bf16x8*)&Q[(size_t)(q0 + ql) * 64 + c * 16 + hi * 8];

    f32x16 o0 = {}, o1 = {};
    float ls = 0.f;

    const int sri = lane >> 3;
    const int sch = lane & 7;

    // wave w stages rows w*8..w*8+7 of K and V tiles (1 instr each)
    auto stage = [&](int buf, int tile) {
        const int kb = tile * 64;
        const int r = w * 8 + sri;
        const int c = sch ^ (r & 7);
        const unsigned short* gk = Kp + (size_t)(kb + r) * 64 + c * 8;
        __builtin_amdgcn_global_load_lds(
            (const __attribute__((address_space(1))) void*)gk,
            (__attribute__((address_space(3))) void*)&Klds[buf][w * 512],
            16, 0, 0);
        const unsigned short* gv = Vt + (size_t)r * 2048 + kb + c * 8;
        __builtin_amdgcn_global_load_lds(
            (const __attribute__((address_space(1))) void*)gv,
            (__attribute__((address_space(3))) void*)&Vlds[buf][w * 512],
            16, 0, 0);
    };

    auto readK = [&](int buf, bf16x8 (&k0)[4], bf16x8 (&k1)[4]) {
        #pragma unroll
        for (int mf = 0; mf < 4; ++mf) {
            int c0 = ((mf * 2 + hi) ^ (ql & 7));
            k0[mf] = *(const bf16x8*)&Klds[buf][ql * 64 + c0 * 8];
            k1[mf] = *(const bf16x8*)&Klds[buf][(32 + ql) * 64 + c0 * 8];
        }
    };

    // prologue: tiles 0,1 staged; QK(0) computed
    stage(0, 0);
    stage(1, 1);
    __syncthreads();
    f32x16 s0c = {}, s1c = {};
    {
        bf16x8 k0[4], k1[4];
        readK(0, k0, k1);
        #pragma unroll
        for (int mf = 0; mf < 4; ++mf)
            s0c = __builtin_amdgcn_mfma_f32_32x32x16_bf16(k0[mf], qb[mf], s0c, 0, 0, 0);
        #pragma unroll
        for (int mf = 0; mf < 4; ++mf)
            s1c = __builtin_amdgcn_mfma_f32_32x32x16_bf16(k1[mf], qb[mf], s1c, 0, 0, 0);
    }

    for (int t = 0; t < 32; ++t) {
        const int bt = t % 3, bt1 = (t + 1) % 3, bt2 = (t + 2) % 3;
        __syncthreads();                       // stage(t+1) landed; tile t-1 reads done
        if (t + 2 < 32) stage(bt2, t + 2);     // overwrite tile t-1's buffer

        // issue ds_reads early: next K, current V
        bf16x8 kn0[4], kn1[4];
        if (t + 1 < 32) readK(bt1, kn0, kn1);
        bf16x8 v0[4], v1[4];
        #pragma unroll
        for (int ks = 0; ks < 4; ++ks) {
            int c0 = ((ks * 2 + hi) ^ (ql & 7));
            v0[ks] = *(const bf16x8*)&Vlds[bt][ql * 64 + c0 * 8];
            v1[ks] = *(const bf16x8*)&Vlds[bt][(32 + ql) * 64 + c0 * 8];
        }

        // QK(t+1) MFMAs issued BEFORE softmax(t): MFMA pipe works under the VALU phase
        f32x16 sn0 = {}, sn1 = {};
        if (t + 1 < 32) {
            #pragma unroll
            for (int mf = 0; mf < 4; ++mf)
                sn0 = __builtin_amdgcn_mfma_f32_32x32x16_bf16(kn0[mf], qb[mf], sn0, 0, 0, 0);
            #pragma unroll
            for (int mf = 0; mf < 4; ++mf)
                sn1 = __builtin_amdgcn_mfma_f32_32x32x16_bf16(kn1[mf], qb[mf], sn1, 0, 0, 0);
        }
        __builtin_amdgcn_sched_barrier(0);     // pin QK issue ahead of softmax

        // softmax(t): max-free, log2 domain
        #pragma unroll
        for (int r = 0; r < 16; ++r) s0c[r] = EXP2(s0c[r]);
        #pragma unroll
        for (int r = 0; r < 16; ++r) s1c[r] = EXP2(s1c[r]);
        float u0 = ((s0c[0] + s0c[1]) + (s0c[2] + s0c[3])) + ((s0c[4] + s0c[5]) + (s0c[6] + s0c[7]));
        float u1 = ((s0c[8] + s0c[9]) + (s0c[10] + s0c[11])) + ((s0c[12] + s0c[13]) + (s0c[14] + s0c[15]));
        float u2 = ((s1c[0] + s1c[1]) + (s1c[2] + s1c[3])) + ((s1c[4] + s1c[5]) + (s1c[6] + s1c[7]));
        float u3 = ((s1c[8] + s1c[9]) + (s1c[10] + s1c[11])) + ((s1c[12] + s1c[13]) + (s1c[14] + s1c[15]));
        float rs = (u0 + u1) + (u2 + u3);
        ls += xhalf_add(rs);

        bf16x8 p0[2], p1[2];
        #pragma unroll
        for (int g = 0; g < 2; ++g) {
            unsigned int x0, x1, x2, x3;
            asm("v_cvt_pk_bf16_f32 %0, %1, %2" : "=v"(x0) : "v"(s0c[8*g + 0]), "v"(s0c[8*g + 1]));
            asm("v_cvt_pk_bf16_f32 %0, %1, %2" : "=v"(x1) : "v"(s0c[8*g + 2]), "v"(s0c[8*g + 3]));
            asm("v_cvt_pk_bf16_f32 %0, %1, %2" : "=v"(x2) : "v"(s0c[8*g + 4]), "v"(s0c[8*g + 5]));
            asm("v_cvt_pk_bf16_f32 %0, %1, %2" : "=v"(x3) : "v"(s0c[8*g + 6]), "v"(s0c[8*g + 7]));
            plswap(x0, x2);
            plswap(x1, x3);
            uint4 wds; wds.x = x0; wds.y = x1; wds.z = x2; wds.w = x3;
            p0[g] = __builtin_bit_cast(bf16x8, wds);
        }
        #pragma unroll
        for (int g = 0; g < 2; ++g) {
            unsigned int x0, x1, x2, x3;
            asm("v_cvt_pk_bf16_f32 %0, %1, %2" : "=v"(x0) : "v"(s1c[8*g + 0]), "v"(s1c[8*g + 1]));
            asm("v_cvt_pk_bf16_f32 %0, %1, %2" : "=v"(x1) : "v"(s1c[8*g + 2]), "v"(s1c[8*g + 3]));
            asm("v_cvt_pk_bf16_f32 %0, %1, %2" : "=v"(x2) : "v"(s1c[8*g + 4]), "v"(s1c[8*g + 5]));
            asm("v_cvt_pk_bf16_f32 %0, %1, %2" : "=v"(x3) : "v"(s1c[8*g + 6]), "v"(s1c[8*g + 7]));
            plswap(x0, x2);
            plswap(x1, x3);
            uint4 wds; wds.x = x0; wds.y = x1; wds.z = x2; wds.w = x3;
            p1[g] = __builtin_bit_cast(bf16x8, wds);
        }

        // PV(t)
        o0 = __builtin_amdgcn_mfma_f32_32x32x16_bf16(v0[0], p0[0], o0, 0, 0, 0);
        o0 = __builtin_amdgcn_mfma_f32_32x32x16_bf16(v0[1], p0[1], o0, 0, 0, 0);
        o0 = __builtin_amdgcn_mfma_f32_32x32x16_bf16(v0[2], p1[0], o0, 0, 0, 0);
        o0 = __builtin_amdgcn_mfma_f32_32x32x16_bf16(v0[3], p1[1], o0, 0, 0, 0);
        o1 = __builtin_amdgcn_mfma_f32_32x32x16_bf16(v1[0], p0[0], o1, 0, 0, 0);
        o1 = __builtin_amdgcn_mfma_f32_32x32x16_bf16(v1[1], p0[1], o1, 0, 0, 0);
        o1 = __builtin_amdgcn_mfma_f32_32x32x16_bf16(v1[2], p1[0], o1, 0, 0, 0);
        o1 = __builtin_amdgcn_mfma_f32_32x32x16_bf16(v1[3], p1[1], o1, 0, 0, 0);

        s0c = sn0;
        s1c = sn1;
    }

    const int b = bh >> 4, h = bh & 15;
    const float inv = 1.0f / ls;
    const int n = q0 + ql;
    unsigned short* obase = out + ((size_t)(b * 2048 + n)) * 1024 + h * 64;
    #pragma unroll
    for (int g = 0; g < 4; ++g) {
        int d0 = 8 * g + 4 * hi;
        ushort4 w0, w1;
        w0.x = f2bf(o0[4 * g + 0] * inv);
        w0.y = f2bf(o0[4 * g + 1] * inv);
        w0.z = f2bf(o0[4 * g + 2] * inv);
        w0.w = f2bf(o0[4 * g + 3] * inv);
        *(ushort4*)(obase + d0) = w0;
        w1.x = f2bf(o1[4 * g + 0] * inv);
        w1.y = f2bf(o1[4 * g + 1] * inv);
        w1.z = f2bf(o1[4 * g + 2] * inv);
        w1.w = f2bf(o1[4 * g + 3] * inv);
        *(ushort4*)(obase + 32 + d0) = w1;
    }
}

// ---------------- launch ----------------
extern "C" void kernel_launch(void* const* d_in, const int* in_sizes, int n_in,
                              void* d_out, int out_size, void* d_ws, size_t ws_size,
                              hipStream_t stream) {
    (void)in_sizes; (void)n_in; (void)out_size; (void)ws_size;
    const float* x     = (const float*)d_in[0];
    const float* w_qkv = (const float*)d_in[1];
    const float* b_qkv = (const float*)d_in[2];
    const float* w_out = (const float*)d_in[3];
    const float* b_out = (const float*)d_in[4];

    unsigned short* ws = (unsigned short*)d_ws;
    unsigned short* xb    = ws;
    unsigned short* wqkvb = ws + 8388608;
    unsigned short* woutb = ws + 11534336;
    unsigned short* qkvb  = ws + 12582912;

    cvt3_kernel<<<dim3(2048), dim3(256), 0, stream>>>(x, w_qkv, w_out, xb, wqkvb, woutb);

    gemm_bt<0><<<dim3(24, 64), dim3(256), 0, stream>>>(xb, wqkvb, b_qkv, (void*)qkvb, 8192, 3072, 1024);

    attn_kernel<<<dim3(512), dim3(512), 0, stream>>>(qkvb, xb);

    gemm_bt<1><<<dim3(8, 64), dim3(256), 0, stream>>>(xb, woutb, b_out, d_out, 8192, 1024, 1024);
}

// Round 16
// 184.487 us; speedup vs baseline: 1.0703x; 1.0703x over previous
//
#include <hip/hip_runtime.h>

typedef __bf16 bf16x8 __attribute__((ext_vector_type(8)));
typedef float f32x4 __attribute__((ext_vector_type(4)));
typedef float f32x16 __attribute__((ext_vector_type(16)));
typedef unsigned int uint2v __attribute__((ext_vector_type(2)));

#define LOG2E 1.44269504088896340736f

#if __has_builtin(__builtin_amdgcn_exp2f)
#define EXP2(x) __builtin_amdgcn_exp2f(x)
#else
#define EXP2(x) exp2f(x)
#endif

static __device__ __forceinline__ unsigned short f2bf(float f) {
    unsigned int u = __builtin_bit_cast(unsigned int, f);
    u += 0x7fffu + ((u >> 16) & 1u);   // RNE
    return (unsigned short)(u >> 16);
}

static __device__ __forceinline__ void plswap(unsigned int& a, unsigned int& b) {
#if __has_builtin(__builtin_amdgcn_permlane32_swap)
    uint2v r = __builtin_amdgcn_permlane32_swap(a, b, false, false);
    a = r.x; b = r.y;
#else
    asm("v_permlane32_swap_b32 %0, %1" : "+v"(a), "+v"(b));
#endif
}

static __device__ __forceinline__ float xhalf_add(float x) {
    unsigned int a = __builtin_bit_cast(unsigned int, x), b = a;
    plswap(a, b);
    return __builtin_bit_cast(float, a) + __builtin_bit_cast(float, b);
}

// ---------------- fused fp32 -> bf16 convert (x | w_qkv | w_out in one launch) ----------------
__global__ void cvt3_kernel(const float* __restrict__ x, const float* __restrict__ wq,
                            const float* __restrict__ wo,
                            unsigned short* __restrict__ xb, unsigned short* __restrict__ wqb,
                            unsigned short* __restrict__ wob) {
    // flat float4 index space: x 2097152 | w_qkv 786432 | w_out 262144 = 3145728
    int i = blockIdx.x * blockDim.x + threadIdx.x;
    int stride = gridDim.x * blockDim.x;
    for (; i < 3145728; i += stride) {
        const float* src;
        unsigned short* dst;
        int j;
        if (i < 2097152)      { j = i;           src = x;  dst = xb;  }
        else if (i < 2883584) { j = i - 2097152; src = wq; dst = wqb; }
        else                  { j = i - 2883584; src = wo; dst = wob; }
        float4 v = reinterpret_cast<const float4*>(src)[j];
        ushort4 o;
        o.x = f2bf(v.x); o.y = f2bf(v.y); o.z = f2bf(v.z); o.w = f2bf(v.w);
        reinterpret_cast<ushort4*>(dst)[j] = o;
    }
}

// ---------------- bf16 GEMM, C = A * B^T (+bias) — r9-proven 2-phase structure ----------------
template <int MODE>
__global__ __launch_bounds__(256, 2) void gemm_bt(const unsigned short* __restrict__ A,
                                                  const unsigned short* __restrict__ B,
                                                  const float* __restrict__ bias,
                                                  void* __restrict__ Cout,
                                                  int M, int N, int K) {
    __shared__ unsigned short SH[2][2][128 * 64];   // [buf][A/B][128x64] = 64 KB
    const int tid = threadIdx.x;
    const int w = tid >> 6, lane = tid & 63;
    const int wr = w >> 1, wc = w & 1;
    const int bm0 = blockIdx.y << 7, bn0 = blockIdx.x << 7;
    const int l15 = lane & 15, l4 = lane >> 4;

    const int srow = w * 8 + (lane >> 3);
    const int gch = (lane & 7) ^ (lane >> 3);

    f32x4 acc[4][4] = {};

    auto stage = [&](int buf, int kt) {
        const int k0 = kt << 6;
        #pragma unroll
        for (int i = 0; i < 4; ++i) {
            int row = i * 32 + srow;
            const unsigned short* ga = A + (size_t)(bm0 + row) * K + k0 + gch * 8;
            __builtin_amdgcn_global_load_lds(
                (const __attribute__((address_space(1))) void*)ga,
                (__attribute__((address_space(3))) void*)&SH[buf][0][i * 2048 + w * 512],
                16, 0, 0);
            const unsigned short* gb = B + (size_t)(bn0 + row) * K + k0 + gch * 8;
            __builtin_amdgcn_global_load_lds(
                (const __attribute__((address_space(1))) void*)gb,
                (__attribute__((address_space(3))) void*)&SH[buf][1][i * 2048 + w * 512],
                16, 0, 0);
        }
    };

    const int nk = K >> 6;
    stage(0, 0);
    __syncthreads();
    int buf = 0;
    for (int kt = 0; kt < nk; ++kt) {
        if (kt + 1 < nk) stage(buf ^ 1, kt + 1);
        const unsigned short* as = &SH[buf][0][0];
        const unsigned short* bs = &SH[buf][1][0];
        #pragma unroll
        for (int s = 0; s < 2; ++s) {
            bf16x8 af[4], bfr[4];
            #pragma unroll
            for (int t = 0; t < 4; ++t) {
                int rowa = wr * 64 + t * 16 + l15;
                int cha = (s * 4 + l4) ^ (rowa & 7);
                af[t] = *(const bf16x8*)&as[rowa * 64 + cha * 8];
                int rowb = wc * 64 + t * 16 + l15;
                int chb = (s * 4 + l4) ^ (rowb & 7);
                bfr[t] = *(const bf16x8*)&bs[rowb * 64 + chb * 8];
            }
            #pragma unroll
            for (int i = 0; i < 4; ++i)
                #pragma unroll
                for (int j = 0; j < 4; ++j)
                    acc[i][j] = __builtin_amdgcn_mfma_f32_16x16x32_bf16(af[i], bfr[j], acc[i][j], 0, 0, 0);
        }
        __syncthreads();
        buf ^= 1;
    }

    if (MODE == 0) {
        unsigned short* O = (unsigned short*)Cout;
        if (bn0 >= 2048) {
            // V region: LDS-bounce transpose -> coalesced uint4 stores
            unsigned short* T = &SH[0][0][0];
            __syncthreads();
            #pragma unroll
            for (int j = 0; j < 4; ++j) {
                int cl = wc * 64 + j * 16 + l15;
                float bv = bias[bn0 + cl];
                #pragma unroll
                for (int i = 0; i < 4; ++i) {
                    int nl = wr * 64 + i * 16 + l4 * 4;
                    ushort4 pk;
                    pk.x = f2bf(acc[i][j][0] + bv);
                    pk.y = f2bf(acc[i][j][1] + bv);
                    pk.z = f2bf(acc[i][j][2] + bv);
                    pk.w = f2bf(acc[i][j][3] + bv);
                    *(ushort4*)&T[cl * 136 + nl] = pk;
                }
            }
            __syncthreads();
            const int b = bm0 >> 11, n0 = bm0 & 2047;
            const int h0 = (bn0 >> 6) & 15;
            #pragma unroll
            for (int it = 0; it < 8; ++it) {
                int dl = it * 16 + (tid >> 4);
                int ch = tid & 15;
                uint4 val = *(const uint4*)&T[dl * 136 + ch * 8];
                size_t idx = (size_t)16777216 +
                             ((size_t)((b * 16 + (h0 + (dl >> 6))) * 64 + (dl & 63))) * 2048 +
                             n0 + ch * 8;
                *(uint4*)&O[idx] = val;
            }
        } else {
            #pragma unroll
            for (int j = 0; j < 4; ++j) {
                int col = bn0 + wc * 64 + j * 16 + l15;
                float bv = bias[col];
                int which = col >> 10;
                int h = (col >> 6) & 15;
                int d = col & 63;
                #pragma unroll
                for (int i = 0; i < 4; ++i) {
                    #pragma unroll
                    for (int r = 0; r < 4; ++r) {
                        int row = bm0 + wr * 64 + i * 16 + l4 * 4 + r;
                        int b = row >> 11, n = row & 2047;
                        float v = acc[i][j][r] + bv;
                        size_t idx;
                        if (which == 0) { v *= 0.125f * LOG2E; idx = ((size_t)((b * 16 + h) * 2048 + n)) * 64 + d; }
                        else { idx = (size_t)8388608 + ((size_t)((b * 16 + h) * 2048 + n)) * 64 + d; }
                        O[idx] = f2bf(v);
                    }
                }
            }
        }
    } else {
        float* C = (float*)Cout;
        #pragma unroll
        for (int j = 0; j < 4; ++j) {
            int col = bn0 + wc * 64 + j * 16 + l15;
            float bv = bias[col];
            #pragma unroll
            for (int i = 0; i < 4; ++i) {
                #pragma unroll
                for (int r = 0; r < 4; ++r) {
                    int row = bm0 + wr * 64 + i * 16 + l4 * 4 + r;
                    C[(size_t)row * N + col] = acc[i][j][r] + bv;
                }
            }
        }
    }
}

// ---------------- flash attention v11: v7 + anti-phase stagger + setprio ----------------
// r13/r14/r15 synthesis: v7(2w/SIMD) == v9(4w/SIMD) == 80.5us; MFMA-busy 30us +
// VALU-busy 38us ~= wall => co-resident blocks are PHASE-LOCKED (identical launch
// time + identical per-iter timing -> all waves in softmax-VALU phase together,
// then MFMA phase together; pipes never overlap). Fix: one-time per-block s_sleep
// stagger (0..2048cy, hash of blockIdx ~ one VALU-phase spread) pushes the two
// blocks sharing each SIMD into antiphase; offset persists (per-block barriers,
// identical iteration durations). T5 setprio(1) around MFMA clusters gives the
// CU scheduler the arbitration lever once roles diverge. No structural change.
__global__ __launch_bounds__(256, 2) void attn_kernel(const unsigned short* __restrict__ qkv,
                                                      unsigned short* __restrict__ out) {
    __shared__ unsigned short Klds[2][4096];   // [64 k-rows][64 d]
    __shared__ unsigned short Vlds[2][4096];   // [64 d-rows][64 n]

    const int tid = threadIdx.x;
    const int w = tid >> 6, lane = tid & 63;
    const int ql = lane & 31;
    const int hi = lane >> 5;
    const int id = blockIdx.x;       // 0..511
    const int bh = id & 63;          // all 8 q-tiles of a head land on one XCD
    const int qt = id >> 6;          // 0..7
    const size_t SEC = 8388608;

    // anti-phase stagger: one-time 0..2048-cycle sleep keyed on block id hash
    {
        const int dly = (id * 37) & 31;        // 0..31 x 64 cyc
        for (int z = 0; z < dly; ++z) __builtin_amdgcn_s_sleep(1);
    }

    const unsigned short* Q  = qkv + (size_t)bh * (2048 * 64);
    const unsigned short* Kp = qkv + SEC + (size_t)bh * (2048 * 64);
    const unsigned short* Vt = qkv + 2 * SEC + (size_t)bh * (64 * 2048);

    const int q0 = qt * 256 + w * 64;

    bf16x8 qbA[4], qbB[4];
    #pragma unroll
    for (int c = 0; c < 4; ++c) {
        qbA[c] = *(const bf16x8*)&Q[(size_t)(q0 + ql) * 64 + c * 16 + hi * 8];
        qbB[c] = *(const bf16x8*)&Q[(size_t)(q0 + 32 + ql) * 64 + c * 16 + hi * 8];
    }

    f32x16 oA0 = {}, oA1 = {}, oB0 = {}, oB1 = {};
    float lsA = 0.f, lsB = 0.f;

    const int sri = lane >> 3;
    const int sch = lane & 7;

    auto stage = [&](int buf, int tile) {
        const int kb = tile * 64;
        #pragma unroll
        for (int i = 0; i < 2; ++i) {
            const int r = w * 16 + i * 8 + sri;
            const int c = sch ^ (r & 7);
            const unsigned short* gk = Kp + (size_t)(kb + r) * 64 + c * 8;
            __builtin_amdgcn_global_load_lds(
                (const __attribute__((address_space(1))) void*)gk,
                (__attribute__((address_space(3))) void*)&Klds[buf][w * 1024 + i * 512],
                16, 0, 0);
            const unsigned short* gv = Vt + (size_t)r * 2048 + kb + c * 8;
            __builtin_amdgcn_global_load_lds(
                (const __attribute__((address_space(1))) void*)gv,
                (__attribute__((address_space(3))) void*)&Vlds[buf][w * 1024 + i * 512],
                16, 0, 0);
        }
    };

    auto softmax_block = [&](f32x16& s0, f32x16& s1, float& lsum,
                             bf16x8 (&p0)[2], bf16x8 (&p1)[2]) {
        #pragma unroll
        for (int r = 0; r < 16; ++r) s0[r] = EXP2(s0[r]);
        #pragma unroll
        for (int r = 0; r < 16; ++r) s1[r] = EXP2(s1[r]);
        float u0 = ((s0[0] + s0[1]) + (s0[2] + s0[3])) + ((s0[4] + s0[5]) + (s0[6] + s0[7]));
        float u1 = ((s0[8] + s0[9]) + (s0[10] + s0[11])) + ((s0[12] + s0[13]) + (s0[14] + s0[15]));
        float u2 = ((s1[0] + s1[1]) + (s1[2] + s1[3])) + ((s1[4] + s1[5]) + (s1[6] + s1[7]));
        float u3 = ((s1[8] + s1[9]) + (s1[10] + s1[11])) + ((s1[12] + s1[13]) + (s1[14] + s1[15]));
        float rs = (u0 + u1) + (u2 + u3);
        lsum += xhalf_add(rs);
        #pragma unroll
        for (int g = 0; g < 2; ++g) {
            unsigned int x0, x1, x2, x3;
            asm("v_cvt_pk_bf16_f32 %0, %1, %2" : "=v"(x0) : "v"(s0[8*g + 0]), "v"(s0[8*g + 1]));
            asm("v_cvt_pk_bf16_f32 %0, %1, %2" : "=v"(x1) : "v"(s0[8*g + 2]), "v"(s0[8*g + 3]));
            asm("v_cvt_pk_bf16_f32 %0, %1, %2" : "=v"(x2) : "v"(s0[8*g + 4]), "v"(s0[8*g + 5]));
            asm("v_cvt_pk_bf16_f32 %0, %1, %2" : "=v"(x3) : "v"(s0[8*g + 6]), "v"(s0[8*g + 7]));
            plswap(x0, x2);
            plswap(x1, x3);
            uint4 wds; wds.x = x0; wds.y = x1; wds.z = x2; wds.w = x3;
            p0[g] = __builtin_bit_cast(bf16x8, wds);
        }
        #pragma unroll
        for (int g = 0; g < 2; ++g) {
            unsigned int x0, x1, x2, x3;
            asm("v_cvt_pk_bf16_f32 %0, %1, %2" : "=v"(x0) : "v"(s1[8*g + 0]), "v"(s1[8*g + 1]));
            asm("v_cvt_pk_bf16_f32 %0, %1, %2" : "=v"(x1) : "v"(s1[8*g + 2]), "v"(s1[8*g + 3]));
            asm("v_cvt_pk_bf16_f32 %0, %1, %2" : "=v"(x2) : "v"(s1[8*g + 4]), "v"(s1[8*g + 5]));
            asm("v_cvt_pk_bf16_f32 %0, %1, %2" : "=v"(x3) : "v"(s1[8*g + 6]), "v"(s1[8*g + 7]));
            plswap(x0, x2);
            plswap(x1, x3);
            uint4 wds; wds.x = x0; wds.y = x1; wds.z = x2; wds.w = x3;
            p1[g] = __builtin_bit_cast(bf16x8, wds);
        }
    };

    stage(0, 0);
    __syncthreads();

    for (int t = 0; t < 32; ++t) {
        const int cur = t & 1;
        if (t + 1 < 32) stage(cur ^ 1, t + 1);

        bf16x8 k0[4], k1[4];
        #pragma unroll
        for (int mf = 0; mf < 4; ++mf) {
            int c0 = ((mf * 2 + hi) ^ (ql & 7));
            k0[mf] = *(const bf16x8*)&Klds[cur][ql * 64 + c0 * 8];
            k1[mf] = *(const bf16x8*)&Klds[cur][(32 + ql) * 64 + c0 * 8];
        }

        __builtin_amdgcn_s_setprio(1);
        f32x16 sA0 = {}, sA1 = {};
        #pragma unroll
        for (int mf = 0; mf < 4; ++mf)
            sA0 = __builtin_amdgcn_mfma_f32_32x32x16_bf16(k0[mf], qbA[mf], sA0, 0, 0, 0);
        #pragma unroll
        for (int mf = 0; mf < 4; ++mf)
            sA1 = __builtin_amdgcn_mfma_f32_32x32x16_bf16(k1[mf], qbA[mf], sA1, 0, 0, 0);
        f32x16 sB0 = {}, sB1 = {};
        #pragma unroll
        for (int mf = 0; mf < 4; ++mf)
            sB0 = __builtin_amdgcn_mfma_f32_32x32x16_bf16(k0[mf], qbB[mf], sB0, 0, 0, 0);
        #pragma unroll
        for (int mf = 0; mf < 4; ++mf)
            sB1 = __builtin_amdgcn_mfma_f32_32x32x16_bf16(k1[mf], qbB[mf], sB1, 0, 0, 0);
        __builtin_amdgcn_s_setprio(0);

        bf16x8 v0[4], v1[4];
        #pragma unroll
        for (int ks = 0; ks < 4; ++ks) {
            int c0 = ((ks * 2 + hi) ^ (ql & 7));
            v0[ks] = *(const bf16x8*)&Vlds[cur][ql * 64 + c0 * 8];
            v1[ks] = *(const bf16x8*)&Vlds[cur][(32 + ql) * 64 + c0 * 8];
        }

        bf16x8 pA0[2], pA1[2], pB0[2], pB1[2];
        softmax_block(sA0, sA1, lsA, pA0, pA1);
        softmax_block(sB0, sB1, lsB, pB0, pB1);

        __builtin_amdgcn_s_setprio(1);
        oA0 = __builtin_amdgcn_mfma_f32_32x32x16_bf16(v0[0], pA0[0], oA0, 0, 0, 0);
        oA0 = __builtin_amdgcn_mfma_f32_32x32x16_bf16(v0[1], pA0[1], oA0, 0, 0, 0);
        oA0 = __builtin_amdgcn_mfma_f32_32x32x16_bf16(v0[2], pA1[0], oA0, 0, 0, 0);
        oA0 = __builtin_amdgcn_mfma_f32_32x32x16_bf16(v0[3], pA1[1], oA0, 0, 0, 0);
        oA1 = __builtin_amdgcn_mfma_f32_32x32x16_bf16(v1[0], pA0[0], oA1, 0, 0, 0);
        oA1 = __builtin_amdgcn_mfma_f32_32x32x16_bf16(v1[1], pA0[1], oA1, 0, 0, 0);
        oA1 = __builtin_amdgcn_mfma_f32_32x32x16_bf16(v1[2], pA1[0], oA1, 0, 0, 0);
        oA1 = __builtin_amdgcn_mfma_f32_32x32x16_bf16(v1[3], pA1[1], oA1, 0, 0, 0);
        oB0 = __builtin_amdgcn_mfma_f32_32x32x16_bf16(v0[0], pB0[0], oB0, 0, 0, 0);
        oB0 = __builtin_amdgcn_mfma_f32_32x32x16_bf16(v0[1], pB0[1], oB0, 0, 0, 0);
        oB0 = __builtin_amdgcn_mfma_f32_32x32x16_bf16(v0[2], pB1[0], oB0, 0, 0, 0);
        oB0 = __builtin_amdgcn_mfma_f32_32x32x16_bf16(v0[3], pB1[1], oB0, 0, 0, 0);
        oB1 = __builtin_amdgcn_mfma_f32_32x32x16_bf16(v1[0], pB0[0], oB1, 0, 0, 0);
        oB1 = __builtin_amdgcn_mfma_f32_32x32x16_bf16(v1[1], pB0[1], oB1, 0, 0, 0);
        oB1 = __builtin_amdgcn_mfma_f32_32x32x16_bf16(v1[2], pB1[0], oB1, 0, 0, 0);
        oB1 = __builtin_amdgcn_mfma_f32_32x32x16_bf16(v1[3], pB1[1], oB1, 0, 0, 0);
        __builtin_amdgcn_s_setprio(0);

        __syncthreads();
    }

    const int b = bh >> 4, h = bh & 15;
    {
        const float inv = 1.0f / lsA;
        const int n = q0 + ql;
        unsigned short* obase = out + ((size_t)(b * 2048 + n)) * 1024 + h * 64;
        #pragma unroll
        for (int g = 0; g < 4; ++g) {
            int d0 = 8 * g + 4 * hi;
            ushort4 w0, w1;
            w0.x = f2bf(oA0[4 * g + 0] * inv);
            w0.y = f2bf(oA0[4 * g + 1] * inv);
            w0.z = f2bf(oA0[4 * g + 2] * inv);
            w0.w = f2bf(oA0[4 * g + 3] * inv);
            *(ushort4*)(obase + d0) = w0;
            w1.x = f2bf(oA1[4 * g + 0] * inv);
            w1.y = f2bf(oA1[4 * g + 1] * inv);
            w1.z = f2bf(oA1[4 * g + 2] * inv);
            w1.w = f2bf(oA1[4 * g + 3] * inv);
            *(ushort4*)(obase + 32 + d0) = w1;
        }
    }
    {
        const float inv = 1.0f / lsB;
        const int n = q0 + 32 + ql;
        unsigned short* obase = out + ((size_t)(b * 2048 + n)) * 1024 + h * 64;
        #pragma unroll
        for (int g = 0; g < 4; ++g) {
            int d0 = 8 * g + 4 * hi;
            ushort4 w0, w1;
            w0.x = f2bf(oB0[4 * g + 0] * inv);
            w0.y = f2bf(oB0[4 * g + 1] * inv);
            w0.z = f2bf(oB0[4 * g + 2] * inv);
            w0.w = f2bf(oB0[4 * g + 3] * inv);
            *(ushort4*)(obase + d0) = w0;
            w1.x = f2bf(oB1[4 * g + 0] * inv);
            w1.y = f2bf(oB1[4 * g + 1] * inv);
            w1.z = f2bf(oB1[4 * g + 2] * inv);
            w1.w = f2bf(oB1[4 * g + 3] * inv);
            *(ushort4*)(obase + 32 + d0) = w1;
        }
    }
}

// ---------------- launch ----------------
extern "C" void kernel_launch(void* const* d_in, const int* in_sizes, int n_in,
                              void* d_out, int out_size, void* d_ws, size_t ws_size,
                              hipStream_t stream) {
    (void)in_sizes; (void)n_in; (void)out_size; (void)ws_size;
    const float* x     = (const float*)d_in[0];
    const float* w_qkv = (const float*)d_in[1];
    const float* b_qkv = (const float*)d_in[2];
    const float* w_out = (const float*)d_in[3];
    const float* b_out = (const float*)d_in[4];

    unsigned short* ws = (unsigned short*)d_ws;
    unsigned short* xb    = ws;
    unsigned short* wqkvb = ws + 8388608;
    unsigned short* woutb = ws + 11534336;
    unsigned short* qkvb  = ws + 12582912;

    cvt3_kernel<<<dim3(2048), dim3(256), 0, stream>>>(x, w_qkv, w_out, xb, wqkvb, woutb);

    gemm_bt<0><<<dim3(24, 64), dim3(256), 0, stream>>>(xb, wqkvb, b_qkv, (void*)qkvb, 8192, 3072, 1024);

    attn_kernel<<<dim3(512), dim3(256), 0, stream>>>(qkvb, xb);

    gemm_bt<1><<<dim3(8, 64), dim3(256), 0, stream>>>(xb, woutb, b_out, d_out, 8192, 1024, 1024);
}

// Round 17
// 180.656 us; speedup vs baseline: 1.0930x; 1.0212x over previous
//
#include <hip/hip_runtime.h>

typedef __bf16 bf16x8 __attribute__((ext_vector_type(8)));
typedef float f32x4 __attribute__((ext_vector_type(4)));
typedef float f32x16 __attribute__((ext_vector_type(16)));
typedef unsigned int uint2v __attribute__((ext_vector_type(2)));

#define LOG2E 1.44269504088896340736f

#if __has_builtin(__builtin_amdgcn_exp2f)
#define EXP2(x) __builtin_amdgcn_exp2f(x)
#else
#define EXP2(x) exp2f(x)
#endif

static __device__ __forceinline__ unsigned short f2bf(float f) {
    unsigned int u = __builtin_bit_cast(unsigned int, f);
    u += 0x7fffu + ((u >> 16) & 1u);   // RNE
    return (unsigned short)(u >> 16);
}

static __device__ __forceinline__ void plswap(unsigned int& a, unsigned int& b) {
#if __has_builtin(__builtin_amdgcn_permlane32_swap)
    uint2v r = __builtin_amdgcn_permlane32_swap(a, b, false, false);
    a = r.x; b = r.y;
#else
    asm("v_permlane32_swap_b32 %0, %1" : "+v"(a), "+v"(b));
#endif
}

// ---------------- fused fp32 -> bf16 convert (x | w_qkv | w_out in one launch) ----------------
__global__ void cvt3_kernel(const float* __restrict__ x, const float* __restrict__ wq,
                            const float* __restrict__ wo,
                            unsigned short* __restrict__ xb, unsigned short* __restrict__ wqb,
                            unsigned short* __restrict__ wob) {
    // flat float4 index space: x 2097152 | w_qkv 786432 | w_out 262144 = 3145728
    int i = blockIdx.x * blockDim.x + threadIdx.x;
    int stride = gridDim.x * blockDim.x;
    for (; i < 3145728; i += stride) {
        const float* src;
        unsigned short* dst;
        int j;
        if (i < 2097152)      { j = i;           src = x;  dst = xb;  }
        else if (i < 2883584) { j = i - 2097152; src = wq; dst = wqb; }
        else                  { j = i - 2883584; src = wo; dst = wob; }
        float4 v = reinterpret_cast<const float4*>(src)[j];
        ushort4 o;
        o.x = f2bf(v.x); o.y = f2bf(v.y); o.z = f2bf(v.z); o.w = f2bf(v.w);
        reinterpret_cast<ushort4*>(dst)[j] = o;
    }
}

// ---------------- bf16 GEMM, C = A * B^T (+bias) — r9-proven 2-phase structure ----------------
template <int MODE>
__global__ __launch_bounds__(256, 2) void gemm_bt(const unsigned short* __restrict__ A,
                                                  const unsigned short* __restrict__ B,
                                                  const float* __restrict__ bias,
                                                  void* __restrict__ Cout,
                                                  int M, int N, int K) {
    __shared__ unsigned short SH[2][2][128 * 64];   // [buf][A/B][128x64] = 64 KB
    const int tid = threadIdx.x;
    const int w = tid >> 6, lane = tid & 63;
    const int wr = w >> 1, wc = w & 1;
    const int bm0 = blockIdx.y << 7, bn0 = blockIdx.x << 7;
    const int l15 = lane & 15, l4 = lane >> 4;

    const int srow = w * 8 + (lane >> 3);
    const int gch = (lane & 7) ^ (lane >> 3);

    f32x4 acc[4][4] = {};

    auto stage = [&](int buf, int kt) {
        const int k0 = kt << 6;
        #pragma unroll
        for (int i = 0; i < 4; ++i) {
            int row = i * 32 + srow;
            const unsigned short* ga = A + (size_t)(bm0 + row) * K + k0 + gch * 8;
            __builtin_amdgcn_global_load_lds(
                (const __attribute__((address_space(1))) void*)ga,
                (__attribute__((address_space(3))) void*)&SH[buf][0][i * 2048 + w * 512],
                16, 0, 0);
            const unsigned short* gb = B + (size_t)(bn0 + row) * K + k0 + gch * 8;
            __builtin_amdgcn_global_load_lds(
                (const __attribute__((address_space(1))) void*)gb,
                (__attribute__((address_space(3))) void*)&SH[buf][1][i * 2048 + w * 512],
                16, 0, 0);
        }
    };

    const int nk = K >> 6;
    stage(0, 0);
    __syncthreads();
    int buf = 0;
    for (int kt = 0; kt < nk; ++kt) {
        if (kt + 1 < nk) stage(buf ^ 1, kt + 1);
        const unsigned short* as = &SH[buf][0][0];
        const unsigned short* bs = &SH[buf][1][0];
        #pragma unroll
        for (int s = 0; s < 2; ++s) {
            bf16x8 af[4], bfr[4];
            #pragma unroll
            for (int t = 0; t < 4; ++t) {
                int rowa = wr * 64 + t * 16 + l15;
                int cha = (s * 4 + l4) ^ (rowa & 7);
                af[t] = *(const bf16x8*)&as[rowa * 64 + cha * 8];
                int rowb = wc * 64 + t * 16 + l15;
                int chb = (s * 4 + l4) ^ (rowb & 7);
                bfr[t] = *(const bf16x8*)&bs[rowb * 64 + chb * 8];
            }
            #pragma unroll
            for (int i = 0; i < 4; ++i)
                #pragma unroll
                for (int j = 0; j < 4; ++j)
                    acc[i][j] = __builtin_amdgcn_mfma_f32_16x16x32_bf16(af[i], bfr[j], acc[i][j], 0, 0, 0);
        }
        __syncthreads();
        buf ^= 1;
    }

    if (MODE == 0) {
        unsigned short* O = (unsigned short*)Cout;
        if (bn0 >= 2048) {
            // V region: LDS-bounce transpose -> coalesced uint4 stores
            unsigned short* T = &SH[0][0][0];
            __syncthreads();
            #pragma unroll
            for (int j = 0; j < 4; ++j) {
                int cl = wc * 64 + j * 16 + l15;
                float bv = bias[bn0 + cl];
                #pragma unroll
                for (int i = 0; i < 4; ++i) {
                    int nl = wr * 64 + i * 16 + l4 * 4;
                    ushort4 pk;
                    pk.x = f2bf(acc[i][j][0] + bv);
                    pk.y = f2bf(acc[i][j][1] + bv);
                    pk.z = f2bf(acc[i][j][2] + bv);
                    pk.w = f2bf(acc[i][j][3] + bv);
                    *(ushort4*)&T[cl * 136 + nl] = pk;
                }
            }
            __syncthreads();
            const int b = bm0 >> 11, n0 = bm0 & 2047;
            const int h0 = (bn0 >> 6) & 15;
            #pragma unroll
            for (int it = 0; it < 8; ++it) {
                int dl = it * 16 + (tid >> 4);
                int ch = tid & 15;
                uint4 val = *(const uint4*)&T[dl * 136 + ch * 8];
                size_t idx = (size_t)16777216 +
                             ((size_t)((b * 16 + (h0 + (dl >> 6))) * 64 + (dl & 63))) * 2048 +
                             n0 + ch * 8;
                *(uint4*)&O[idx] = val;
            }
        } else {
            #pragma unroll
            for (int j = 0; j < 4; ++j) {
                int col = bn0 + wc * 64 + j * 16 + l15;
                float bv = bias[col];
                int which = col >> 10;
                int h = (col >> 6) & 15;
                int d = col & 63;
                #pragma unroll
                for (int i = 0; i < 4; ++i) {
                    #pragma unroll
                    for (int r = 0; r < 4; ++r) {
                        int row = bm0 + wr * 64 + i * 16 + l4 * 4 + r;
                        int b = row >> 11, n = row & 2047;
                        float v = acc[i][j][r] + bv;
                        size_t idx;
                        if (which == 0) { v *= 0.125f * LOG2E; idx = ((size_t)((b * 16 + h) * 2048 + n)) * 64 + d; }
                        else { idx = (size_t)8388608 + ((size_t)((b * 16 + h) * 2048 + n)) * 64 + d; }
                        O[idx] = f2bf(v);
                    }
                }
            }
        }
    } else {
        float* C = (float*)Cout;
        #pragma unroll
        for (int j = 0; j < 4; ++j) {
            int col = bn0 + wc * 64 + j * 16 + l15;
            float bv = bias[col];
            #pragma unroll
            for (int i = 0; i < 4; ++i) {
                #pragma unroll
                for (int r = 0; r < 4; ++r) {
                    int row = bm0 + wr * 64 + i * 16 + l4 * 4 + r;
                    C[(size_t)row * N + col] = acc[i][j][r] + bv;
                }
            }
        }
    }
}

// ---------------- flash attention v12: r13's v7 + lsum via ones-row MFMA ----------------
// lsum = sum_k P[k,q] computed by mfma(A=ones, B=P^T): every output reg of the
// 32x32 C tile equals the column sum for q=lane&31, accumulated across tiles for
// free. Deletes the per-iter 54-add tree + 2 permlane-adds from the VALU path
// (~8% of VALU-busy) for 8 extra MFMA issues/iter on the 37%-utilized MFMA pipe.
// Numerics: sums the SAME bf16 P that PV consumes. No sync/structure change vs r13.
__global__ __launch_bounds__(256, 2) void attn_kernel(const unsigned short* __restrict__ qkv,
                                                      unsigned short* __restrict__ out) {
    __shared__ unsigned short Klds[2][4096];   // [64 k-rows][64 d]
    __shared__ unsigned short Vlds[2][4096];   // [64 d-rows][64 n]

    const int tid = threadIdx.x;
    const int w = tid >> 6, lane = tid & 63;
    const int ql = lane & 31;
    const int hi = lane >> 5;
    const int id = blockIdx.x;       // 0..511
    const int bh = id & 63;          // all 8 q-tiles of a head land on one XCD
    const int qt = id >> 6;          // 0..7
    const size_t SEC = 8388608;

    const unsigned short* Q  = qkv + (size_t)bh * (2048 * 64);
    const unsigned short* Kp = qkv + SEC + (size_t)bh * (2048 * 64);
    const unsigned short* Vt = qkv + 2 * SEC + (size_t)bh * (64 * 2048);

    const int q0 = qt * 256 + w * 64;

    bf16x8 qbA[4], qbB[4];
    #pragma unroll
    for (int c = 0; c < 4; ++c) {
        qbA[c] = *(const bf16x8*)&Q[(size_t)(q0 + ql) * 64 + c * 16 + hi * 8];
        qbB[c] = *(const bf16x8*)&Q[(size_t)(q0 + 32 + ql) * 64 + c * 16 + hi * 8];
    }

    // all-ones bf16 A-fragment for the lsum MFMA
    uint4 onesw;
    onesw.x = 0x3F803F80u; onesw.y = 0x3F803F80u; onesw.z = 0x3F803F80u; onesw.w = 0x3F803F80u;
    const bf16x8 ones = __builtin_bit_cast(bf16x8, onesw);

    f32x16 oA0 = {}, oA1 = {}, oB0 = {}, oB1 = {};
    f32x16 lAacc = {}, lBacc = {};

    const int sri = lane >> 3;
    const int sch = lane & 7;

    auto stage = [&](int buf, int tile) {
        const int kb = tile * 64;
        #pragma unroll
        for (int i = 0; i < 2; ++i) {
            const int r = w * 16 + i * 8 + sri;
            const int c = sch ^ (r & 7);
            const unsigned short* gk = Kp + (size_t)(kb + r) * 64 + c * 8;
            __builtin_amdgcn_global_load_lds(
                (const __attribute__((address_space(1))) void*)gk,
                (__attribute__((address_space(3))) void*)&Klds[buf][w * 1024 + i * 512],
                16, 0, 0);
            const unsigned short* gv = Vt + (size_t)r * 2048 + kb + c * 8;
            __builtin_amdgcn_global_load_lds(
                (const __attribute__((address_space(1))) void*)gv,
                (__attribute__((address_space(3))) void*)&Vlds[buf][w * 1024 + i * 512],
                16, 0, 0);
        }
    };

    // exp2 in place + T12 relayout (no sum tree: lsum comes from ones-MFMA)
    auto softmax_block = [&](f32x16& s0, f32x16& s1,
                             bf16x8 (&p0)[2], bf16x8 (&p1)[2]) {
        #pragma unroll
        for (int r = 0; r < 16; ++r) s0[r] = EXP2(s0[r]);
        #pragma unroll
        for (int r = 0; r < 16; ++r) s1[r] = EXP2(s1[r]);
        #pragma unroll
        for (int g = 0; g < 2; ++g) {
            unsigned int x0, x1, x2, x3;
            asm("v_cvt_pk_bf16_f32 %0, %1, %2" : "=v"(x0) : "v"(s0[8*g + 0]), "v"(s0[8*g + 1]));
            asm("v_cvt_pk_bf16_f32 %0, %1, %2" : "=v"(x1) : "v"(s0[8*g + 2]), "v"(s0[8*g + 3]));
            asm("v_cvt_pk_bf16_f32 %0, %1, %2" : "=v"(x2) : "v"(s0[8*g + 4]), "v"(s0[8*g + 5]));
            asm("v_cvt_pk_bf16_f32 %0, %1, %2" : "=v"(x3) : "v"(s0[8*g + 6]), "v"(s0[8*g + 7]));
            plswap(x0, x2);
            plswap(x1, x3);
            uint4 wds; wds.x = x0; wds.y = x1; wds.z = x2; wds.w = x3;
            p0[g] = __builtin_bit_cast(bf16x8, wds);
        }
        #pragma unroll
        for (int g = 0; g < 2; ++g) {
            unsigned int x0, x1, x2, x3;
            asm("v_cvt_pk_bf16_f32 %0, %1, %2" : "=v"(x0) : "v"(s1[8*g + 0]), "v"(s1[8*g + 1]));
            asm("v_cvt_pk_bf16_f32 %0, %1, %2" : "=v"(x1) : "v"(s1[8*g + 2]), "v"(s1[8*g + 3]));
            asm("v_cvt_pk_bf16_f32 %0, %1, %2" : "=v"(x2) : "v"(s1[8*g + 4]), "v"(s1[8*g + 5]));
            asm("v_cvt_pk_bf16_f32 %0, %1, %2" : "=v"(x3) : "v"(s1[8*g + 6]), "v"(s1[8*g + 7]));
            plswap(x0, x2);
            plswap(x1, x3);
            uint4 wds; wds.x = x0; wds.y = x1; wds.z = x2; wds.w = x3;
            p1[g] = __builtin_bit_cast(bf16x8, wds);
        }
    };

    stage(0, 0);
    __syncthreads();

    for (int t = 0; t < 32; ++t) {
        const int cur = t & 1;
        if (t + 1 < 32) stage(cur ^ 1, t + 1);

        bf16x8 k0[4], k1[4];
        #pragma unroll
        for (int mf = 0; mf < 4; ++mf) {
            int c0 = ((mf * 2 + hi) ^ (ql & 7));
            k0[mf] = *(const bf16x8*)&Klds[cur][ql * 64 + c0 * 8];
            k1[mf] = *(const bf16x8*)&Klds[cur][(32 + ql) * 64 + c0 * 8];
        }

        f32x16 sA0 = {}, sA1 = {};
        #pragma unroll
        for (int mf = 0; mf < 4; ++mf)
            sA0 = __builtin_amdgcn_mfma_f32_32x32x16_bf16(k0[mf], qbA[mf], sA0, 0, 0, 0);
        #pragma unroll
        for (int mf = 0; mf < 4; ++mf)
            sA1 = __builtin_amdgcn_mfma_f32_32x32x16_bf16(k1[mf], qbA[mf], sA1, 0, 0, 0);
        f32x16 sB0 = {}, sB1 = {};
        #pragma unroll
        for (int mf = 0; mf < 4; ++mf)
            sB0 = __builtin_amdgcn_mfma_f32_32x32x16_bf16(k0[mf], qbB[mf], sB0, 0, 0, 0);
        #pragma unroll
        for (int mf = 0; mf < 4; ++mf)
            sB1 = __builtin_amdgcn_mfma_f32_32x32x16_bf16(k1[mf], qbB[mf], sB1, 0, 0, 0);

        bf16x8 v0[4], v1[4];
        #pragma unroll
        for (int ks = 0; ks < 4; ++ks) {
            int c0 = ((ks * 2 + hi) ^ (ql & 7));
            v0[ks] = *(const bf16x8*)&Vlds[cur][ql * 64 + c0 * 8];
            v1[ks] = *(const bf16x8*)&Vlds[cur][(32 + ql) * 64 + c0 * 8];
        }

        bf16x8 pA0[2], pA1[2], pB0[2], pB1[2];
        softmax_block(sA0, sA1, pA0, pA1);
        softmax_block(sB0, sB1, pB0, pB1);

        // lsum accumulators: ones-row x P^T (every reg = column sum for q=lane&31)
        lAacc = __builtin_amdgcn_mfma_f32_32x32x16_bf16(ones, pA0[0], lAacc, 0, 0, 0);
        lAacc = __builtin_amdgcn_mfma_f32_32x32x16_bf16(ones, pA0[1], lAacc, 0, 0, 0);
        lAacc = __builtin_amdgcn_mfma_f32_32x32x16_bf16(ones, pA1[0], lAacc, 0, 0, 0);
        lAacc = __builtin_amdgcn_mfma_f32_32x32x16_bf16(ones, pA1[1], lAacc, 0, 0, 0);
        lBacc = __builtin_amdgcn_mfma_f32_32x32x16_bf16(ones, pB0[0], lBacc, 0, 0, 0);
        lBacc = __builtin_amdgcn_mfma_f32_32x32x16_bf16(ones, pB0[1], lBacc, 0, 0, 0);
        lBacc = __builtin_amdgcn_mfma_f32_32x32x16_bf16(ones, pB1[0], lBacc, 0, 0, 0);
        lBacc = __builtin_amdgcn_mfma_f32_32x32x16_bf16(ones, pB1[1], lBacc, 0, 0, 0);

        oA0 = __builtin_amdgcn_mfma_f32_32x32x16_bf16(v0[0], pA0[0], oA0, 0, 0, 0);
        oA0 = __builtin_amdgcn_mfma_f32_32x32x16_bf16(v0[1], pA0[1], oA0, 0, 0, 0);
        oA0 = __builtin_amdgcn_mfma_f32_32x32x16_bf16(v0[2], pA1[0], oA0, 0, 0, 0);
        oA0 = __builtin_amdgcn_mfma_f32_32x32x16_bf16(v0[3], pA1[1], oA0, 0, 0, 0);
        oA1 = __builtin_amdgcn_mfma_f32_32x32x16_bf16(v1[0], pA0[0], oA1, 0, 0, 0);
        oA1 = __builtin_amdgcn_mfma_f32_32x32x16_bf16(v1[1], pA0[1], oA1, 0, 0, 0);
        oA1 = __builtin_amdgcn_mfma_f32_32x32x16_bf16(v1[2], pA1[0], oA1, 0, 0, 0);
        oA1 = __builtin_amdgcn_mfma_f32_32x32x16_bf16(v1[3], pA1[1], oA1, 0, 0, 0);
        oB0 = __builtin_amdgcn_mfma_f32_32x32x16_bf16(v0[0], pB0[0], oB0, 0, 0, 0);
        oB0 = __builtin_amdgcn_mfma_f32_32x32x16_bf16(v0[1], pB0[1], oB0, 0, 0, 0);
        oB0 = __builtin_amdgcn_mfma_f32_32x32x16_bf16(v0[2], pB1[0], oB0, 0, 0, 0);
        oB0 = __builtin_amdgcn_mfma_f32_32x32x16_bf16(v0[3], pB1[1], oB0, 0, 0, 0);
        oB1 = __builtin_amdgcn_mfma_f32_32x32x16_bf16(v1[0], pB0[0], oB1, 0, 0, 0);
        oB1 = __builtin_amdgcn_mfma_f32_32x32x16_bf16(v1[1], pB0[1], oB1, 0, 0, 0);
        oB1 = __builtin_amdgcn_mfma_f32_32x32x16_bf16(v1[2], pB1[0], oB1, 0, 0, 0);
        oB1 = __builtin_amdgcn_mfma_f32_32x32x16_bf16(v1[3], pB1[1], oB1, 0, 0, 0);

        __syncthreads();
    }

    const int b = bh >> 4, h = bh & 15;
    {
        const float inv = 1.0f / lAacc[0];
        const int n = q0 + ql;
        unsigned short* obase = out + ((size_t)(b * 2048 + n)) * 1024 + h * 64;
        #pragma unroll
        for (int g = 0; g < 4; ++g) {
            int d0 = 8 * g + 4 * hi;
            ushort4 w0, w1;
            w0.x = f2bf(oA0[4 * g + 0] * inv);
            w0.y = f2bf(oA0[4 * g + 1] * inv);
            w0.z = f2bf(oA0[4 * g + 2] * inv);
            w0.w = f2bf(oA0[4 * g + 3] * inv);
            *(ushort4*)(obase + d0) = w0;
            w1.x = f2bf(oA1[4 * g + 0] * inv);
            w1.y = f2bf(oA1[4 * g + 1] * inv);
            w1.z = f2bf(oA1[4 * g + 2] * inv);
            w1.w = f2bf(oA1[4 * g + 3] * inv);
            *(ushort4*)(obase + 32 + d0) = w1;
        }
    }
    {
        const float inv = 1.0f / lBacc[0];
        const int n = q0 + 32 + ql;
        unsigned short* obase = out + ((size_t)(b * 2048 + n)) * 1024 + h * 64;
        #pragma unroll
        for (int g = 0; g < 4; ++g) {
            int d0 = 8 * g + 4 * hi;
            ushort4 w0, w1;
            w0.x = f2bf(oB0[4 * g + 0] * inv);
            w0.y = f2bf(oB0[4 * g + 1] * inv);
            w0.z = f2bf(oB0[4 * g + 2] * inv);
            w0.w = f2bf(oB0[4 * g + 3] * inv);
            *(ushort4*)(obase + d0) = w0;
            w1.x = f2bf(oB1[4 * g + 0] * inv);
            w1.y = f2bf(oB1[4 * g + 1] * inv);
            w1.z = f2bf(oB1[4 * g + 2] * inv);
            w1.w = f2bf(oB1[4 * g + 3] * inv);
            *(ushort4*)(obase + 32 + d0) = w1;
        }
    }
}

// ---------------- launch ----------------
extern "C" void kernel_launch(void* const* d_in, const int* in_sizes, int n_in,
                              void* d_out, int out_size, void* d_ws, size_t ws_size,
                              hipStream_t stream) {
    (void)in_sizes; (void)n_in; (void)out_size; (void)ws_size;
    const float* x     = (const float*)d_in[0];
    const float* w_qkv = (const float*)d_in[1];
    const float* b_qkv = (const float*)d_in[2];
    const float* w_out = (const float*)d_in[3];
    const float* b_out = (const float*)d_in[4];

    unsigned short* ws = (unsigned short*)d_ws;
    unsigned short* xb    = ws;
    unsigned short* wqkvb = ws + 8388608;
    unsigned short* woutb = ws + 11534336;
    unsigned short* qkvb  = ws + 12582912;

    cvt3_kernel<<<dim3(2048), dim3(256), 0, stream>>>(x, w_qkv, w_out, xb, wqkvb, woutb);

    gemm_bt<0><<<dim3(24, 64), dim3(256), 0, stream>>>(xb, wqkvb, b_qkv, (void*)qkvb, 8192, 3072, 1024);

    attn_kernel<<<dim3(512), dim3(256), 0, stream>>>(qkvb, xb);

    gemm_bt<1><<<dim3(8, 64), dim3(256), 0, stream>>>(xb, woutb, b_out, d_out, 8192, 1024, 1024);
}

// Round 18
// 175.898 us; speedup vs baseline: 1.1226x; 1.0270x over previous
//
#include <hip/hip_runtime.h>

typedef __bf16 bf16x8 __attribute__((ext_vector_type(8)));
typedef float f32x4 __attribute__((ext_vector_type(4)));
typedef float f32x16 __attribute__((ext_vector_type(16)));
typedef unsigned int uint2v __attribute__((ext_vector_type(2)));

#define LOG2E 1.44269504088896340736f

#if __has_builtin(__builtin_amdgcn_exp2f)
#define EXP2(x) __builtin_amdgcn_exp2f(x)
#else
#define EXP2(x) exp2f(x)
#endif

static __device__ __forceinline__ unsigned short f2bf(float f) {
    unsigned int u = __builtin_bit_cast(unsigned int, f);
    u += 0x7fffu + ((u >> 16) & 1u);   // RNE
    return (unsigned short)(u >> 16);
}

static __device__ __forceinline__ void plswap(unsigned int& a, unsigned int& b) {
#if __has_builtin(__builtin_amdgcn_permlane32_swap)
    uint2v r = __builtin_amdgcn_permlane32_swap(a, b, false, false);
    a = r.x; b = r.y;
#else
    asm("v_permlane32_swap_b32 %0, %1" : "+v"(a), "+v"(b));
#endif
}

static __device__ __forceinline__ float xhalf_add(float x) {
    unsigned int a = __builtin_bit_cast(unsigned int, x), b = a;
    plswap(a, b);
    return __builtin_bit_cast(float, a) + __builtin_bit_cast(float, b);
}

// ---------------- fused fp32 -> bf16 convert (x | w_qkv | w_out in one launch) ----------------
__global__ void cvt3_kernel(const float* __restrict__ x, const float* __restrict__ wq,
                            const float* __restrict__ wo,
                            unsigned short* __restrict__ xb, unsigned short* __restrict__ wqb,
                            unsigned short* __restrict__ wob) {
    // flat float4 index space: x 2097152 | w_qkv 786432 | w_out 262144 = 3145728
    int i = blockIdx.x * blockDim.x + threadIdx.x;
    int stride = gridDim.x * blockDim.x;
    for (; i < 3145728; i += stride) {
        const float* src;
        unsigned short* dst;
        int j;
        if (i < 2097152)      { j = i;           src = x;  dst = xb;  }
        else if (i < 2883584) { j = i - 2097152; src = wq; dst = wqb; }
        else                  { j = i - 2883584; src = wo; dst = wob; }
        float4 v = reinterpret_cast<const float4*>(src)[j];
        ushort4 o;
        o.x = f2bf(v.x); o.y = f2bf(v.y); o.z = f2bf(v.z); o.w = f2bf(v.w);
        reinterpret_cast<ushort4*>(dst)[j] = o;
    }
}

// ---------------- bf16 GEMM, C = A * B^T (+bias) — r9-proven 2-phase structure ----------------
template <int MODE>
__global__ __launch_bounds__(256, 2) void gemm_bt(const unsigned short* __restrict__ A,
                                                  const unsigned short* __restrict__ B,
                                                  const float* __restrict__ bias,
                                                  void* __restrict__ Cout,
                                                  int M, int N, int K) {
    __shared__ unsigned short SH[2][2][128 * 64];   // [buf][A/B][128x64] = 64 KB
    const int tid = threadIdx.x;
    const int w = tid >> 6, lane = tid & 63;
    const int wr = w >> 1, wc = w & 1;
    const int bm0 = blockIdx.y << 7, bn0 = blockIdx.x << 7;
    const int l15 = lane & 15, l4 = lane >> 4;

    const int srow = w * 8 + (lane >> 3);
    const int gch = (lane & 7) ^ (lane >> 3);

    f32x4 acc[4][4] = {};

    auto stage = [&](int buf, int kt) {
        const int k0 = kt << 6;
        #pragma unroll
        for (int i = 0; i < 4; ++i) {
            int row = i * 32 + srow;
            const unsigned short* ga = A + (size_t)(bm0 + row) * K + k0 + gch * 8;
            __builtin_amdgcn_global_load_lds(
                (const __attribute__((address_space(1))) void*)ga,
                (__attribute__((address_space(3))) void*)&SH[buf][0][i * 2048 + w * 512],
                16, 0, 0);
            const unsigned short* gb = B + (size_t)(bn0 + row) * K + k0 + gch * 8;
            __builtin_amdgcn_global_load_lds(
                (const __attribute__((address_space(1))) void*)gb,
                (__attribute__((address_space(3))) void*)&SH[buf][1][i * 2048 + w * 512],
                16, 0, 0);
        }
    };

    const int nk = K >> 6;
    stage(0, 0);
    __syncthreads();
    int buf = 0;
    for (int kt = 0; kt < nk; ++kt) {
        if (kt + 1 < nk) stage(buf ^ 1, kt + 1);
        const unsigned short* as = &SH[buf][0][0];
        const unsigned short* bs = &SH[buf][1][0];
        #pragma unroll
        for (int s = 0; s < 2; ++s) {
            bf16x8 af[4], bfr[4];
            #pragma unroll
            for (int t = 0; t < 4; ++t) {
                int rowa = wr * 64 + t * 16 + l15;
                int cha = (s * 4 + l4) ^ (rowa & 7);
                af[t] = *(const bf16x8*)&as[rowa * 64 + cha * 8];
                int rowb = wc * 64 + t * 16 + l15;
                int chb = (s * 4 + l4) ^ (rowb & 7);
                bfr[t] = *(const bf16x8*)&bs[rowb * 64 + chb * 8];
            }
            #pragma unroll
            for (int i = 0; i < 4; ++i)
                #pragma unroll
                for (int j = 0; j < 4; ++j)
                    acc[i][j] = __builtin_amdgcn_mfma_f32_16x16x32_bf16(af[i], bfr[j], acc[i][j], 0, 0, 0);
        }
        __syncthreads();
        buf ^= 1;
    }

    if (MODE == 0) {
        unsigned short* O = (unsigned short*)Cout;
        if (bn0 >= 2048) {
            // V region: LDS-bounce transpose -> coalesced uint4 stores
            unsigned short* T = &SH[0][0][0];
            __syncthreads();
            #pragma unroll
            for (int j = 0; j < 4; ++j) {
                int cl = wc * 64 + j * 16 + l15;
                float bv = bias[bn0 + cl];
                #pragma unroll
                for (int i = 0; i < 4; ++i) {
                    int nl = wr * 64 + i * 16 + l4 * 4;
                    ushort4 pk;
                    pk.x = f2bf(acc[i][j][0] + bv);
                    pk.y = f2bf(acc[i][j][1] + bv);
                    pk.z = f2bf(acc[i][j][2] + bv);
                    pk.w = f2bf(acc[i][j][3] + bv);
                    *(ushort4*)&T[cl * 136 + nl] = pk;
                }
            }
            __syncthreads();
            const int b = bm0 >> 11, n0 = bm0 & 2047;
            const int h0 = (bn0 >> 6) & 15;
            #pragma unroll
            for (int it = 0; it < 8; ++it) {
                int dl = it * 16 + (tid >> 4);
                int ch = tid & 15;
                uint4 val = *(const uint4*)&T[dl * 136 + ch * 8];
                size_t idx = (size_t)16777216 +
                             ((size_t)((b * 16 + (h0 + (dl >> 6))) * 64 + (dl & 63))) * 2048 +
                             n0 + ch * 8;
                *(uint4*)&O[idx] = val;
            }
        } else {
            #pragma unroll
            for (int j = 0; j < 4; ++j) {
                int col = bn0 + wc * 64 + j * 16 + l15;
                float bv = bias[col];
                int which = col >> 10;
                int h = (col >> 6) & 15;
                int d = col & 63;
                #pragma unroll
                for (int i = 0; i < 4; ++i) {
                    #pragma unroll
                    for (int r = 0; r < 4; ++r) {
                        int row = bm0 + wr * 64 + i * 16 + l4 * 4 + r;
                        int b = row >> 11, n = row & 2047;
                        float v = acc[i][j][r] + bv;
                        size_t idx;
                        if (which == 0) { v *= 0.125f * LOG2E; idx = ((size_t)((b * 16 + h) * 2048 + n)) * 64 + d; }
                        else { idx = (size_t)8388608 + ((size_t)((b * 16 + h) * 2048 + n)) * 64 + d; }
                        O[idx] = f2bf(v);
                    }
                }
            }
        }
    } else {
        float* C = (float*)Cout;
        #pragma unroll
        for (int j = 0; j < 4; ++j) {
            int col = bn0 + wc * 64 + j * 16 + l15;
            float bv = bias[col];
            #pragma unroll
            for (int i = 0; i < 4; ++i) {
                #pragma unroll
                for (int r = 0; r < 4; ++r) {
                    int row = bm0 + wr * 64 + i * 16 + l4 * 4 + r;
                    C[(size_t)row * N + col] = acc[i][j][r] + bv;
                }
            }
        }
    }
}

// ---------------- flash attention v7 (r13-proven): 64 q/wave, no online max ----------------
__global__ __launch_bounds__(256, 2) void attn_kernel(const unsigned short* __restrict__ qkv,
                                                      unsigned short* __restrict__ out) {
    __shared__ unsigned short Klds[2][4096];   // [64 k-rows][64 d]
    __shared__ unsigned short Vlds[2][4096];   // [64 d-rows][64 n]

    const int tid = threadIdx.x;
    const int w = tid >> 6, lane = tid & 63;
    const int ql = lane & 31;
    const int hi = lane >> 5;
    const int id = blockIdx.x;       // 0..511
    const int bh = id & 63;          // all 8 q-tiles of a head land on one XCD
    const int qt = id >> 6;          // 0..7
    const size_t SEC = 8388608;

    const unsigned short* Q  = qkv + (size_t)bh * (2048 * 64);
    const unsigned short* Kp = qkv + SEC + (size_t)bh * (2048 * 64);
    const unsigned short* Vt = qkv + 2 * SEC + (size_t)bh * (64 * 2048);

    const int q0 = qt * 256 + w * 64;

    bf16x8 qbA[4], qbB[4];
    #pragma unroll
    for (int c = 0; c < 4; ++c) {
        qbA[c] = *(const bf16x8*)&Q[(size_t)(q0 + ql) * 64 + c * 16 + hi * 8];
        qbB[c] = *(const bf16x8*)&Q[(size_t)(q0 + 32 + ql) * 64 + c * 16 + hi * 8];
    }

    f32x16 oA0 = {}, oA1 = {}, oB0 = {}, oB1 = {};
    float lsA = 0.f, lsB = 0.f;

    const int sri = lane >> 3;
    const int sch = lane & 7;

    auto stage = [&](int buf, int tile) {
        const int kb = tile * 64;
        #pragma unroll
        for (int i = 0; i < 2; ++i) {
            const int r = w * 16 + i * 8 + sri;
            const int c = sch ^ (r & 7);
            const unsigned short* gk = Kp + (size_t)(kb + r) * 64 + c * 8;
            __builtin_amdgcn_global_load_lds(
                (const __attribute__((address_space(1))) void*)gk,
                (__attribute__((address_space(3))) void*)&Klds[buf][w * 1024 + i * 512],
                16, 0, 0);
            const unsigned short* gv = Vt + (size_t)r * 2048 + kb + c * 8;
            __builtin_amdgcn_global_load_lds(
                (const __attribute__((address_space(1))) void*)gv,
                (__attribute__((address_space(3))) void*)&Vlds[buf][w * 1024 + i * 512],
                16, 0, 0);
        }
    };

    auto softmax_block = [&](f32x16& s0, f32x16& s1, float& lsum,
                             bf16x8 (&p0)[2], bf16x8 (&p1)[2]) {
        #pragma unroll
        for (int r = 0; r < 16; ++r) s0[r] = EXP2(s0[r]);
        #pragma unroll
        for (int r = 0; r < 16; ++r) s1[r] = EXP2(s1[r]);
        float u0 = ((s0[0] + s0[1]) + (s0[2] + s0[3])) + ((s0[4] + s0[5]) + (s0[6] + s0[7]));
        float u1 = ((s0[8] + s0[9]) + (s0[10] + s0[11])) + ((s0[12] + s0[13]) + (s0[14] + s0[15]));
        float u2 = ((s1[0] + s1[1]) + (s1[2] + s1[3])) + ((s1[4] + s1[5]) + (s1[6] + s1[7]));
        float u3 = ((s1[8] + s1[9]) + (s1[10] + s1[11])) + ((s1[12] + s1[13]) + (s1[14] + s1[15]));
        float rs = (u0 + u1) + (u2 + u3);
        lsum += xhalf_add(rs);
        #pragma unroll
        for (int g = 0; g < 2; ++g) {
            unsigned int x0, x1, x2, x3;
            asm("v_cvt_pk_bf16_f32 %0, %1, %2" : "=v"(x0) : "v"(s0[8*g + 0]), "v"(s0[8*g + 1]));
            asm("v_cvt_pk_bf16_f32 %0, %1, %2" : "=v"(x1) : "v"(s0[8*g + 2]), "v"(s0[8*g + 3]));
            asm("v_cvt_pk_bf16_f32 %0, %1, %2" : "=v"(x2) : "v"(s0[8*g + 4]), "v"(s0[8*g + 5]));
            asm("v_cvt_pk_bf16_f32 %0, %1, %2" : "=v"(x3) : "v"(s0[8*g + 6]), "v"(s0[8*g + 7]));
            plswap(x0, x2);
            plswap(x1, x3);
            uint4 wds; wds.x = x0; wds.y = x1; wds.z = x2; wds.w = x3;
            p0[g] = __builtin_bit_cast(bf16x8, wds);
        }
        #pragma unroll
        for (int g = 0; g < 2; ++g) {
            unsigned int x0, x1, x2, x3;
            asm("v_cvt_pk_bf16_f32 %0, %1, %2" : "=v"(x0) : "v"(s1[8*g + 0]), "v"(s1[8*g + 1]));
            asm("v_cvt_pk_bf16_f32 %0, %1, %2" : "=v"(x1) : "v"(s1[8*g + 2]), "v"(s1[8*g + 3]));
            asm("v_cvt_pk_bf16_f32 %0, %1, %2" : "=v"(x2) : "v"(s1[8*g + 4]), "v"(s1[8*g + 5]));
            asm("v_cvt_pk_bf16_f32 %0, %1, %2" : "=v"(x3) : "v"(s1[8*g + 6]), "v"(s1[8*g + 7]));
            plswap(x0, x2);
            plswap(x1, x3);
            uint4 wds; wds.x = x0; wds.y = x1; wds.z = x2; wds.w = x3;
            p1[g] = __builtin_bit_cast(bf16x8, wds);
        }
    };

    stage(0, 0);
    __syncthreads();

    for (int t = 0; t < 32; ++t) {
        const int cur = t & 1;
        if (t + 1 < 32) stage(cur ^ 1, t + 1);

        bf16x8 k0[4], k1[4];
        #pragma unroll
        for (int mf = 0; mf < 4; ++mf) {
            int c0 = ((mf * 2 + hi) ^ (ql & 7));
            k0[mf] = *(const bf16x8*)&Klds[cur][ql * 64 + c0 * 8];
            k1[mf] = *(const bf16x8*)&Klds[cur][(32 + ql) * 64 + c0 * 8];
        }

        f32x16 sA0 = {}, sA1 = {};
        #pragma unroll
        for (int mf = 0; mf < 4; ++mf)
            sA0 = __builtin_amdgcn_mfma_f32_32x32x16_bf16(k0[mf], qbA[mf], sA0, 0, 0, 0);
        #pragma unroll
        for (int mf = 0; mf < 4; ++mf)
            sA1 = __builtin_amdgcn_mfma_f32_32x32x16_bf16(k1[mf], qbA[mf], sA1, 0, 0, 0);
        f32x16 sB0 = {}, sB1 = {};
        #pragma unroll
        for (int mf = 0; mf < 4; ++mf)
            sB0 = __builtin_amdgcn_mfma_f32_32x32x16_bf16(k0[mf], qbB[mf], sB0, 0, 0, 0);
        #pragma unroll
        for (int mf = 0; mf < 4; ++mf)
            sB1 = __builtin_amdgcn_mfma_f32_32x32x16_bf16(k1[mf], qbB[mf], sB1, 0, 0, 0);

        bf16x8 v0[4], v1[4];
        #pragma unroll
        for (int ks = 0; ks < 4; ++ks) {
            int c0 = ((ks * 2 + hi) ^ (ql & 7));
            v0[ks] = *(const bf16x8*)&Vlds[cur][ql * 64 + c0 * 8];
            v1[ks] = *(const bf16x8*)&Vlds[cur][(32 + ql) * 64 + c0 * 8];
        }

        bf16x8 pA0[2], pA1[2], pB0[2], pB1[2];
        softmax_block(sA0, sA1, lsA, pA0, pA1);
        softmax_block(sB0, sB1, lsB, pB0, pB1);

        oA0 = __builtin_amdgcn_mfma_f32_32x32x16_bf16(v0[0], pA0[0], oA0, 0, 0, 0);
        oA0 = __builtin_amdgcn_mfma_f32_32x32x16_bf16(v0[1], pA0[1], oA0, 0, 0, 0);
        oA0 = __builtin_amdgcn_mfma_f32_32x32x16_bf16(v0[2], pA1[0], oA0, 0, 0, 0);
        oA0 = __builtin_amdgcn_mfma_f32_32x32x16_bf16(v0[3], pA1[1], oA0, 0, 0, 0);
        oA1 = __builtin_amdgcn_mfma_f32_32x32x16_bf16(v1[0], pA0[0], oA1, 0, 0, 0);
        oA1 = __builtin_amdgcn_mfma_f32_32x32x16_bf16(v1[1], pA0[1], oA1, 0, 0, 0);
        oA1 = __builtin_amdgcn_mfma_f32_32x32x16_bf16(v1[2], pA1[0], oA1, 0, 0, 0);
        oA1 = __builtin_amdgcn_mfma_f32_32x32x16_bf16(v1[3], pA1[1], oA1, 0, 0, 0);
        oB0 = __builtin_amdgcn_mfma_f32_32x32x16_bf16(v0[0], pB0[0], oB0, 0, 0, 0);
        oB0 = __builtin_amdgcn_mfma_f32_32x32x16_bf16(v0[1], pB0[1], oB0, 0, 0, 0);
        oB0 = __builtin_amdgcn_mfma_f32_32x32x16_bf16(v0[2], pB1[0], oB0, 0, 0, 0);
        oB0 = __builtin_amdgcn_mfma_f32_32x32x16_bf16(v0[3], pB1[1], oB0, 0, 0, 0);
        oB1 = __builtin_amdgcn_mfma_f32_32x32x16_bf16(v1[0], pB0[0], oB1, 0, 0, 0);
        oB1 = __builtin_amdgcn_mfma_f32_32x32x16_bf16(v1[1], pB0[1], oB1, 0, 0, 0);
        oB1 = __builtin_amdgcn_mfma_f32_32x32x16_bf16(v1[2], pB1[0], oB1, 0, 0, 0);
        oB1 = __builtin_amdgcn_mfma_f32_32x32x16_bf16(v1[3], pB1[1], oB1, 0, 0, 0);

        __syncthreads();
    }

    const int b = bh >> 4, h = bh & 15;
    {
        const float inv = 1.0f / lsA;
        const int n = q0 + ql;
        unsigned short* obase = out + ((size_t)(b * 2048 + n)) * 1024 + h * 64;
        #pragma unroll
        for (int g = 0; g < 4; ++g) {
            int d0 = 8 * g + 4 * hi;
            ushort4 w0, w1;
            w0.x = f2bf(oA0[4 * g + 0] * inv);
            w0.y = f2bf(oA0[4 * g + 1] * inv);
            w0.z = f2bf(oA0[4 * g + 2] * inv);
            w0.w = f2bf(oA0[4 * g + 3] * inv);
            *(ushort4*)(obase + d0) = w0;
            w1.x = f2bf(oA1[4 * g + 0] * inv);
            w1.y = f2bf(oA1[4 * g + 1] * inv);
            w1.z = f2bf(oA1[4 * g + 2] * inv);
            w1.w = f2bf(oA1[4 * g + 3] * inv);
            *(ushort4*)(obase + 32 + d0) = w1;
        }
    }
    {
        const float inv = 1.0f / lsB;
        const int n = q0 + 32 + ql;
        unsigned short* obase = out + ((size_t)(b * 2048 + n)) * 1024 + h * 64;
        #pragma unroll
        for (int g = 0; g < 4; ++g) {
            int d0 = 8 * g + 4 * hi;
            ushort4 w0, w1;
            w0.x = f2bf(oB0[4 * g + 0] * inv);
            w0.y = f2bf(oB0[4 * g + 1] * inv);
            w0.z = f2bf(oB0[4 * g + 2] * inv);
            w0.w = f2bf(oB0[4 * g + 3] * inv);
            *(ushort4*)(obase + d0) = w0;
            w1.x = f2bf(oB1[4 * g + 0] * inv);
            w1.y = f2bf(oB1[4 * g + 1] * inv);
            w1.z = f2bf(oB1[4 * g + 2] * inv);
            w1.w = f2bf(oB1[4 * g + 3] * inv);
            *(ushort4*)(obase + 32 + d0) = w1;
        }
    }
}

// ---------------- launch ----------------
extern "C" void kernel_launch(void* const* d_in, const int* in_sizes, int n_in,
                              void* d_out, int out_size, void* d_ws, size_t ws_size,
                              hipStream_t stream) {
    (void)in_sizes; (void)n_in; (void)out_size; (void)ws_size;
    const float* x     = (const float*)d_in[0];
    const float* w_qkv = (const float*)d_in[1];
    const float* b_qkv = (const float*)d_in[2];
    const float* w_out = (const float*)d_in[3];
    const float* b_out = (const float*)d_in[4];

    unsigned short* ws = (unsigned short*)d_ws;
    unsigned short* xb    = ws;
    unsigned short* wqkvb = ws + 8388608;
    unsigned short* woutb = ws + 11534336;
    unsigned short* qkvb  = ws + 12582912;

    cvt3_kernel<<<dim3(2048), dim3(256), 0, stream>>>(x, w_qkv, w_out, xb, wqkvb, woutb);

    gemm_bt<0><<<dim3(24, 64), dim3(256), 0, stream>>>(xb, wqkvb, b_qkv, (void*)qkvb, 8192, 3072, 1024);

    attn_kernel<<<dim3(512), dim3(256), 0, stream>>>(qkvb, xb);

    gemm_bt<1><<<dim3(8, 64), dim3(256), 0, stream>>>(xb, woutb, b_out, d_out, 8192, 1024, 1024);
}